// Round 7
// baseline (96.621 us; speedup 1.0000x reference)
//
#include <hip/hip_runtime.h>
#include <hip/hip_bf16.h>

// y = x @ W^T + b ; x:(16,8192,256) f32, W:(256,256) f32, b:(256,) f32, out f32
// M=131072, N=256, K=256. Memory-bound.
// R7 = R6 (operand-swapped MFMA -> row-major lane output -> dwordx4 nt stores),
//      fixed: __builtin_nontemporal_store needs clang ext_vector, not HIP float4.
// History: R2 grid>512 hurts; R3 transposed global loads = VMEM death;
//   R4 barrier restructure hurt; R5 nt stores +3us (FETCH unchanged -> keep).

typedef __attribute__((ext_vector_type(8))) short bf16x8;
typedef __attribute__((ext_vector_type(16))) float f32x16;
typedef __attribute__((ext_vector_type(4)))  float f32x4;

__device__ __forceinline__ short f2bf(float f) {
    __hip_bfloat16 h = __float2bfloat16(f);   // RTNE
    return *reinterpret_cast<short*>(&h);
}

#define BM   32
#define LDSK 264   // 256 + 8 pad: 528B row stride -> conflict-free b128 frag reads

__global__ __launch_bounds__(512, 4)
void rac_linear_kernel(const float* __restrict__ x,
                       const float* __restrict__ w,
                       const float* __restrict__ bias,
                       float* __restrict__ out,
                       int tiles_per_block)
{
    __shared__ short lds[2][BM * LDSK];   // 2 x 16.5 KB

    const int tid  = threadIdx.x;
    const int lane = tid & 63;
    const int wv   = tid >> 6;        // 0..7: N-wave, owns cols [wv*32, wv*32+32)
    const int l31  = lane & 31;
    const int lh   = lane >> 5;       // 0/1: k-half of the fragment

    // ---- B prologue: W[n][k] -> per-wave bf16 register fragments ----
    // Fragment layout (A and B identical): idx = lane&31, k = (lane>>5)*8 + j
    bf16x8 bfrag[16];
    {
        const int   wrow = wv * 32 + l31;                 // n index
        const float* wb  = w + (size_t)wrow * 256 + lh * 8;
        #pragma unroll
        for (int ks = 0; ks < 16; ++ks) {
            const float4 lo = *reinterpret_cast<const float4*>(wb + ks * 16);
            const float4 hi = *reinterpret_cast<const float4*>(wb + ks * 16 + 4);
            bf16x8 b;
            b[0]=f2bf(lo.x); b[1]=f2bf(lo.y); b[2]=f2bf(lo.z); b[3]=f2bf(lo.w);
            b[4]=f2bf(hi.x); b[5]=f2bf(hi.y); b[6]=f2bf(hi.z); b[7]=f2bf(hi.w);
            bfrag[ks] = b;
        }
    }

    // per-reg bias: swapped-D layout has n = (r&3) + 8*(r>>2) + 4*lh
    float bv[16];
    #pragma unroll
    for (int r = 0; r < 16; ++r)
        bv[r] = bias[wv * 32 + (r & 3) + 8 * (r >> 2) + 4 * lh];

    const int t0 = blockIdx.x * tiles_per_block;

    float4 v[4];   // staging registers (one BM x 256 f32 tile = 64 B/thread)

    // prologue: load + stage tile t0 into buf 0
    {
        const float4* src = reinterpret_cast<const float4*>(x + (size_t)t0 * (BM * 256));
        #pragma unroll
        for (int i = 0; i < 4; ++i) v[i] = src[i * 512 + tid];   // fully coalesced
        #pragma unroll
        for (int i = 0; i < 4; ++i) {
            const int row = i * 8 + (tid >> 6);      // elem = i*2048 + tid*4
            const int k   = (tid & 63) * 4;
            short4 s;
            s.x=f2bf(v[i].x); s.y=f2bf(v[i].y); s.z=f2bf(v[i].z); s.w=f2bf(v[i].w);
            *reinterpret_cast<short4*>(&lds[0][row * LDSK + k]) = s;
        }
    }

    for (int t = 0; t < tiles_per_block; ++t) {
        const int buf  = t & 1;
        const int tile = t0 + t;
        __syncthreads();   // staged buf visible; prev compute on buf^1 done

        // issue next tile's global loads early (latency hidden under compute)
        if (t + 1 < tiles_per_block) {
            const float4* src =
                reinterpret_cast<const float4*>(x + (size_t)(tile + 1) * (BM * 256));
            #pragma unroll
            for (int i = 0; i < 4; ++i) v[i] = src[i * 512 + tid];
        }

        // ---- compute: 16 K-steps, SWAPPED operands -> D = C^T ----
        f32x16 acc;
        #pragma unroll
        for (int r = 0; r < 16; ++r) acc[r] = bv[r];

        const short* abase = &lds[buf][l31 * LDSK + lh * 8];
        #pragma unroll
        for (int ks = 0; ks < 16; ++ks) {
            bf16x8 a = *reinterpret_cast<const bf16x8*>(abase + ks * 16);
            acc = __builtin_amdgcn_mfma_f32_32x32x16_bf16(bfrag[ks], a, acc, 0, 0, 0);
        }

        // ---- epilogue: lane owns OUTPUT ROW m = lane&31;
        //      n = (r&3) + 8*(r>>2) + 4*lh -> 4 contiguous float4 runs ----
        {
            float* ob = out + (size_t)tile * (BM * 256) + (size_t)l31 * 256
                            + wv * 32 + lh * 4;
            #pragma unroll
            for (int g = 0; g < 4; ++g) {
                f32x4 s;
                s[0] = acc[g * 4 + 0]; s[1] = acc[g * 4 + 1];
                s[2] = acc[g * 4 + 2]; s[3] = acc[g * 4 + 3];
                __builtin_nontemporal_store(s, reinterpret_cast<f32x4*>(ob + g * 8));
            }
        }

        // stage next tile into the other buffer (safe: all waves past barrier)
        if (t + 1 < tiles_per_block) {
            #pragma unroll
            for (int i = 0; i < 4; ++i) {
                const int row = i * 8 + (tid >> 6);
                const int k   = (tid & 63) * 4;
                short4 s;
                s.x=f2bf(v[i].x); s.y=f2bf(v[i].y); s.z=f2bf(v[i].z); s.w=f2bf(v[i].w);
                *reinterpret_cast<short4*>(&lds[buf ^ 1][row * LDSK + k]) = s;
            }
        }
    }
}

extern "C" void kernel_launch(void* const* d_in, const int* in_sizes, int n_in,
                              void* d_out, int out_size, void* d_ws, size_t ws_size,
                              hipStream_t stream)
{
    const float* x    = (const float*)d_in[0];
    const float* w    = (const float*)d_in[1];
    const float* bias = (const float*)d_in[2];
    float* out        = (float*)d_out;

    const int M      = in_sizes[0] / 256;   // 131072 rows
    const int ntiles = M / BM;              // 4096
    const int grid   = 512;                 // 2 blocks/CU (R2: more blocks hurt)
    const int tpb    = ntiles / grid;       // 8 tiles per block

    rac_linear_kernel<<<grid, 512, 0, stream>>>(x, w, bias, out, tpb);
}

// Round 8
// 58.788 us; speedup vs baseline: 1.6435x; 1.6435x over previous
//
#include <hip/hip_runtime.h>
#include <hip/hip_bf16.h>

// y = x @ W^T + b ; x:(16,8192,256) f32, W:(256,256) f32, b:(256,) f32, out f32
// M=131072, N=256, K=256. Memory-bound.
// R8 = R5 (best, 58.8us) with ONE change: per-iter __syncthreads() replaced by
//      raw `s_waitcnt lgkmcnt(0); s_barrier` -> stores + load slack are NOT
//      drained at the barrier (compiler's __syncthreads emits vmcnt(0)).
// Safety: only cross-wave dep at barrier is LDS staging (lgkmcnt covers);
//      prefetch loads are consumed by ds_write BEFORE the barrier (counted
//      vmcnt emitted by compiler); stores never read back; acc WAR tracked.
// History: R2 grid>512 hurts; R3 transposed global loads = 32 lines/instr =
//      VMEM death; R4 restructure hurt (confounded); R5 nt +3us;
//      R7 row-per-lane dwordx4 nt stores = partial-line write amplification
//      (134->244MB) -> full-line coverage per store instr is mandatory.

typedef __attribute__((ext_vector_type(8))) short bf16x8;
typedef __attribute__((ext_vector_type(16))) float f32x16;

__device__ __forceinline__ short f2bf(float f) {
    __hip_bfloat16 h = __float2bfloat16(f);   // RTNE
    return *reinterpret_cast<short*>(&h);
}

#define BM   32
#define LDSK 264   // 256 + 8 pad: 528B row stride -> conflict-free b128 frag reads

__global__ __launch_bounds__(512, 4)
void rac_linear_kernel(const float* __restrict__ x,
                       const float* __restrict__ w,
                       const float* __restrict__ bias,
                       float* __restrict__ out,
                       int tiles_per_block)
{
    __shared__ short lds[2][BM * LDSK];   // 2 x 16.5 KB

    const int tid  = threadIdx.x;
    const int lane = tid & 63;
    const int wv   = tid >> 6;        // 0..7: N-wave, owns cols [wv*32, wv*32+32)
    const int l31  = lane & 31;
    const int lh   = lane >> 5;       // 0/1: k-half of the fragment

    // ---- B prologue: W[n][k] -> per-wave bf16 register fragments ----
    // B frag layout (32x32x16): col = lane&31 (n), k = (lane>>5)*8 + j
    bf16x8 bfrag[16];
    {
        const int   wrow = wv * 32 + l31;                 // n index
        const float* wb  = w + (size_t)wrow * 256 + lh * 8;
        #pragma unroll
        for (int ks = 0; ks < 16; ++ks) {
            const float4 lo = *reinterpret_cast<const float4*>(wb + ks * 16);
            const float4 hi = *reinterpret_cast<const float4*>(wb + ks * 16 + 4);
            bf16x8 b;
            b[0]=f2bf(lo.x); b[1]=f2bf(lo.y); b[2]=f2bf(lo.z); b[3]=f2bf(lo.w);
            b[4]=f2bf(hi.x); b[5]=f2bf(hi.y); b[6]=f2bf(hi.z); b[7]=f2bf(hi.w);
            bfrag[ks] = b;
        }
    }
    const float bval = bias[wv * 32 + l31];

    const int t0 = blockIdx.x * tiles_per_block;

    float4 v[4];   // staging registers (one BM x 256 f32 tile = 64 B/thread)

    // prologue: load + stage tile t0 into buf 0
    {
        const float4* src = reinterpret_cast<const float4*>(x + (size_t)t0 * (BM * 256));
        #pragma unroll
        for (int i = 0; i < 4; ++i) v[i] = src[i * 512 + tid];   // fully coalesced
        #pragma unroll
        for (int i = 0; i < 4; ++i) {
            const int row = i * 8 + (tid >> 6);      // elem = i*2048 + tid*4
            const int k   = (tid & 63) * 4;
            short4 s;
            s.x=f2bf(v[i].x); s.y=f2bf(v[i].y); s.z=f2bf(v[i].z); s.w=f2bf(v[i].w);
            *reinterpret_cast<short4*>(&lds[0][row * LDSK + k]) = s;
        }
    }

    for (int t = 0; t < tiles_per_block; ++t) {
        const int buf  = t & 1;
        const int tile = t0 + t;

        // LDS-visibility barrier only (no vmcnt drain: stores + prefetch loads
        // stay in flight across iterations).
        asm volatile("s_waitcnt lgkmcnt(0)\n\ts_barrier" ::: "memory");

        // issue next tile's global loads early (latency hidden under compute)
        if (t + 1 < tiles_per_block) {
            const float4* src =
                reinterpret_cast<const float4*>(x + (size_t)(tile + 1) * (BM * 256));
            #pragma unroll
            for (int i = 0; i < 4; ++i) v[i] = src[i * 512 + tid];
        }

        // ---- compute: 16 K-steps of mfma_f32_32x32x16_bf16 ----
        f32x16 acc;
        #pragma unroll
        for (int r = 0; r < 16; ++r) acc[r] = bval;

        // A frag layout: row = lane&31 (m), k = (lane>>5)*8 + j
        const short* abase = &lds[buf][l31 * LDSK + lh * 8];
        #pragma unroll
        for (int ks = 0; ks < 16; ++ks) {
            bf16x8 a = *reinterpret_cast<const bf16x8*>(abase + ks * 16);
            acc = __builtin_amdgcn_mfma_f32_32x32x16_bf16(a, bfrag[ks], acc, 0, 0, 0);
        }

        // ---- epilogue: C layout col=lane&31, row=(r&3)+8*(r>>2)+4*(lane>>5) ----
        // 32 lanes sweep one output row -> every store instr covers full 128B
        // lines (R7 lesson). NONTEMPORAL: out has no reuse.
        {
            float* ob = out + (size_t)tile * (BM * 256) + wv * 32 + l31;
            const int rhi = lh * 4;
            #pragma unroll
            for (int r = 0; r < 16; ++r) {
                const int row = (r & 3) + 8 * (r >> 2) + rhi;
                __builtin_nontemporal_store(acc[r], &ob[(size_t)row * 256]);
            }
        }

        // stage next tile into the other buffer (safe: all waves past barrier)
        if (t + 1 < tiles_per_block) {
            #pragma unroll
            for (int i = 0; i < 4; ++i) {
                const int row = i * 8 + (tid >> 6);
                const int k   = (tid & 63) * 4;
                short4 s;
                s.x=f2bf(v[i].x); s.y=f2bf(v[i].y); s.z=f2bf(v[i].z); s.w=f2bf(v[i].w);
                *reinterpret_cast<short4*>(&lds[buf ^ 1][row * LDSK + k]) = s;
            }
        }
    }
}

extern "C" void kernel_launch(void* const* d_in, const int* in_sizes, int n_in,
                              void* d_out, int out_size, void* d_ws, size_t ws_size,
                              hipStream_t stream)
{
    const float* x    = (const float*)d_in[0];
    const float* w    = (const float*)d_in[1];
    const float* bias = (const float*)d_in[2];
    float* out        = (float*)d_out;

    const int M      = in_sizes[0] / 256;   // 131072 rows
    const int ntiles = M / BM;              // 4096
    const int grid   = 512;                 // 2 blocks/CU (R2: more blocks hurt)
    const int tpb    = ntiles / grid;       // 8 tiles per block

    rac_linear_kernel<<<grid, 512, 0, stream>>>(x, w, bias, out, tpb);
}